// Round 1
// baseline (94.822 us; speedup 1.0000x reference)
//
#include <hip/hip_runtime.h>
#include <math.h>

// Problem shapes (fixed by setup_inputs)
constexpr int B = 16, T = 1000, P = 64, STR = 6, SCALE = 64;
constexpr int S = T * SCALE;        // 64000 samples per batch row
constexpr int SEG_PITCH = 1024;     // padded pitch for 1001 segment bases
#define NYQ 11025.0f
#define INV_SR (1.0f / 22050.0f)

__device__ __forceinline__ float fracf_(float x) {
#if __has_builtin(__builtin_amdgcn_fractf)
  return __builtin_amdgcn_fractf(x);
#else
  return x - floorf(x);
#endif
}

__device__ __forceinline__ float sin2pi(float r) {
  // r in [0,1): v_sin_f32 takes revolutions on gfx950
#if __has_builtin(__builtin_amdgcn_sinf)
  return __builtin_amdgcn_sinf(r);
#else
  return __sinf(r * 6.28318530717958647692f);
#endif
}

// Kernel 1: per batch row b, exclusive prefix of segment sums of the
// upsampled f0 (fundamental only; partial p scales phase by (p+1)).
// Segments: g=0 head (32 samples @ F0), g=1..999 middle (64 samples,
// linear F[g-1]->F[g]), g=1000 tail start base. Accumulate in fp64
// (units: Hz*samples), divide by SR, reduce mod 1, store fp32.
__global__ __launch_bounds__(256) void k_segbase(
    const float* __restrict__ six_f0, const int* __restrict__ sidx_p,
    float* __restrict__ segbase) {
  const int b = blockIdx.x;
  const int tid = threadIdx.x;
  const int sidx = sidx_p[0] - 1;

  __shared__ float Fs[T];
  for (int t = tid; t < T; t += 256)
    Fs[t] = six_f0[(size_t)(b * T + t) * STR + sidx];
  __syncthreads();

  // each thread owns segments g in [4*tid, 4*tid+4)
  double loc[4];
  double run = 0.0;
#pragma unroll
  for (int j = 0; j < 4; ++j) {
    int g = 4 * tid + j;
    double ssum = 0.0;
    if (g == 0)
      ssum = 32.0 * (double)Fs[0];
    else if (g <= T - 1)
      ssum = 32.0 * ((double)Fs[g - 1] + (double)Fs[g]);
    else if (g == T)
      ssum = 32.0 * (double)Fs[T - 1];
    loc[j] = run;   // exclusive within thread
    run += ssum;
  }

  // block-level exclusive scan of per-thread totals (4 waves of 64)
  const int lane = tid & 63, wid = tid >> 6;
  double v = run;
  for (int off = 1; off < 64; off <<= 1) {
    double n = __shfl_up(v, off, 64);
    if (lane >= off) v += n;
  }
  __shared__ double wtot[4];
  if (lane == 63) wtot[wid] = v;
  __syncthreads();
  double excl = v - run;
  for (int w = 0; w < wid; ++w) excl += wtot[w];

#pragma unroll
  for (int j = 0; j < 4; ++j) {
    int g = 4 * tid + j;
    if (g <= T) {
      double ph = (excl + loc[j]) / 22050.0;
      ph -= floor(ph);  // keep fractional phase: sin is 1-periodic in revs
      segbase[b * SEG_PITCH + g] = (float)ph;
    }
  }
}

// Kernel 2: one block = one b and 256 consecutive output samples.
// Stage the <=6 needed amplitude columns (Nyquist-masked) in LDS, then
// per-thread closed-form phase + loop over live partials.
__global__ __launch_bounds__(256) void k_synth(
    const float* __restrict__ six_f0, const float* __restrict__ c,
    const float* __restrict__ a, const int* __restrict__ sidx_p,
    const float* __restrict__ segbase, float* __restrict__ out) {
  const int b = blockIdx.y;
  const int s0 = blockIdx.x * 256;
  const int tid = threadIdx.x;
  const int sidx = sidx_p[0] - 1;
  const float* cb = c + (size_t)sidx * B * P * T;
  const float* loud = a + (size_t)sidx * B * T + (size_t)b * T;

  // frame window this block touches
  const int g0 = (s0 + 32) >> 6;
  const int g3 = (s0 + 255 + 32) >> 6;
  const int fmin = max(g0 - 1, 0);
  const int fmax = min(g3, T - 1);
  const int nf = fmax - fmin + 1;  // <= 6

  __shared__ float Fsh[8];
  __shared__ float amps[8][64];  // [frame][partial], Nyquist-masked

  if (tid < nf)
    Fsh[tid] = six_f0[(size_t)(b * T + fmin + tid) * STR + sidx];
  __syncthreads();

  for (int i = tid; i < 512; i += 256) {
    int p = i >> 3, f = i & 7;
    if (f < nf) {
      float cv = cb[((size_t)b * P + p) * T + fmin + f];
      float F = Fsh[f];
      amps[f][p] = ((float)(p + 1) * F < NYQ) ? cv : 0.0f;
    }
  }
  __syncthreads();

  const int s = s0 + tid;
  const int g = (s + 32) >> 6;                    // segment id, 0..1000
  const int lo = (g == 0) ? 0 : (g - 1);          // = i0 of the upsample
  const int hi = min(g, T - 1);                   // = i1
  const int segstart = (g == 0) ? 0 : ((g << 6) - 32);
  const int k = s - segstart;                     // local sample in segment
  const float kf1 = (float)(k + 1);

  const float Flo = Fsh[lo - fmin];
  const float Fhi = Fsh[hi - fmin];
  const float base = segbase[b * SEG_PITCH + g];
  // inclusive within-segment phase: sum_{j<=k} [Flo + (j+.5)/64*dF] / SR
  const float local =
      (kf1 * Flo + (Fhi - Flo) * kf1 * kf1 * (1.0f / 128.0f)) * INV_SR;
  const float phi = fracf_(base + local);
  const float w = ((float)k + 0.5f) * (1.0f / 64.0f);
  const float l0 = loud[lo];
  const float lup = l0 + w * (loud[hi] - l0);

  // partials above Nyquist have amp==0 in LDS; cap the loop
  const float Fmn = fminf(Flo, Fhi);
  const int pmax = min(P, (int)(NYQ / Fmn) + 1);

  const int lo_l = lo - fmin, hi_l = hi - fmin;
  float acc = 0.0f, pf = 1.0f;
#pragma unroll 4
  for (int p = 0; p < pmax; ++p) {
    float a0 = amps[lo_l][p];
    float a1 = amps[hi_l][p];
    float amp = a0 + w * (a1 - a0);
    float r = fracf_(pf * phi);  // frac((p+1)*phi): exact mod-1 scaling
    acc = fmaf(sin2pi(r), amp, acc);
    pf += 1.0f;
  }
  out[(size_t)b * S + s] = acc * 0.02f * lup;
}

extern "C" void kernel_launch(void* const* d_in, const int* in_sizes, int n_in,
                              void* d_out, int out_size, void* d_ws,
                              size_t ws_size, hipStream_t stream) {
  const float* six_f0 = (const float*)d_in[0];
  const float* c = (const float*)d_in[1];
  const float* a = (const float*)d_in[2];
  const int* sidx = (const int*)d_in[3];
  float* out = (float*)d_out;
  float* segbase = (float*)d_ws;  // B * SEG_PITCH floats = 64 KiB

  hipLaunchKernelGGL(k_segbase, dim3(B), dim3(256), 0, stream, six_f0, sidx,
                     segbase);
  hipLaunchKernelGGL(k_synth, dim3(S / 256, B), dim3(256), 0, stream, six_f0,
                     c, a, sidx, segbase, out);
}

// Round 2
// 87.298 us; speedup vs baseline: 1.0862x; 1.0862x over previous
//
#include <hip/hip_runtime.h>
#include <math.h>

// Problem shapes (fixed by setup_inputs)
constexpr int B = 16, T = 1000, P = 64, STR = 6, SCALE = 64;
constexpr int S = T * SCALE;     // 64000 samples per batch row
constexpr int SEG_PITCH = 1024;  // padded pitch for 1001 segment bases
constexpr int SEGS_PER_BLK = 16; // segments per synth block
constexpr int NF = 17;           // frame columns staged per block (16 segs + 1)
constexpr int NBLK = 63;         // ceil(1001/16)
#define NYQ 11025.0f
#define INV_SR (1.0f / 22050.0f)

__device__ __forceinline__ float fracf_(float x) {
#if __has_builtin(__builtin_amdgcn_fractf)
  return __builtin_amdgcn_fractf(x);
#else
  return x - floorf(x);
#endif
}
__device__ __forceinline__ float sin2pi(float r) {
#if __has_builtin(__builtin_amdgcn_sinf)
  return __builtin_amdgcn_sinf(r);  // v_sin_f32: input in revolutions
#else
  return __sinf(r * 6.28318530717958647692f);
#endif
}
__device__ __forceinline__ float cos2pi(float r) {
#if __has_builtin(__builtin_amdgcn_cosf)
  return __builtin_amdgcn_cosf(r);
#else
  return __cosf(r * 6.28318530717958647692f);
#endif
}

// Kernel 1: per batch row b, exclusive prefix (mod 1) of segment phase sums of
// the upsampled fundamental. Segment g=0: 32 samples @F0; g=1..999: 64 samples
// linear F[g-1]->F[g] (sum = 32*(Flo+Fhi)); g=1000 tail. fp64 accumulate.
__global__ __launch_bounds__(256) void k_segbase(
    const float* __restrict__ six_f0, const int* __restrict__ sidx_p,
    float* __restrict__ segbase) {
  const int b = blockIdx.x;
  const int tid = threadIdx.x;
  const int sidx = sidx_p[0] - 1;

  __shared__ float Fs[T];
  for (int t = tid; t < T; t += 256)
    Fs[t] = six_f0[(size_t)(b * T + t) * STR + sidx];
  __syncthreads();

  double loc[4];
  double run = 0.0;
#pragma unroll
  for (int j = 0; j < 4; ++j) {
    int g = 4 * tid + j;
    double ssum = 0.0;
    if (g == 0)
      ssum = 32.0 * (double)Fs[0];
    else if (g <= T - 1)
      ssum = 32.0 * ((double)Fs[g - 1] + (double)Fs[g]);
    else if (g == T)
      ssum = 32.0 * (double)Fs[T - 1];
    loc[j] = run;
    run += ssum;
  }

  const int lane = tid & 63, wid = tid >> 6;
  double v = run;
  for (int off = 1; off < 64; off <<= 1) {
    double n = __shfl_up(v, off, 64);
    if (lane >= off) v += n;
  }
  __shared__ double wtot[4];
  if (lane == 63) wtot[wid] = v;
  __syncthreads();
  double excl = v - run;
  for (int w = 0; w < wid; ++w) excl += wtot[w];

#pragma unroll
  for (int j = 0; j < 4; ++j) {
    int g = 4 * tid + j;
    if (g <= T) {
      double ph = (excl + loc[j]) / 22050.0;
      ph -= floor(ph);
      segbase[b * SEG_PITCH + g] = (float)ph;
    }
  }
}

// Kernel 2: block = (b, 16 consecutive segments). Thread owns 4 consecutive
// samples inside ONE segment -> shared (a0,a1) pair per partial, one
// ds_read2_b32. Phase via Chebyshev recurrence: no per-iteration sin.
__global__ __launch_bounds__(256) void k_synth(
    const float* __restrict__ six_f0, const float* __restrict__ c,
    const float* __restrict__ a, const int* __restrict__ sidx_p,
    const float* __restrict__ segbase, float* __restrict__ out) {
  const int b = blockIdx.y;
  const int G0 = blockIdx.x * SEGS_PER_BLK;  // first segment of this block
  const int fbase = G0 - 1;                  // frame of LDS column 0 (clamped)
  const int tid = threadIdx.x;
  const int sidx = sidx_p[0] - 1;
  const float* cb = c + (size_t)sidx * B * P * T;
  const float* loud = a + (size_t)sidx * B * T + (size_t)b * T;

  __shared__ float Fsh[NF];
  __shared__ float Lsh[NF];
  __shared__ float ampsT[P][NF + 1];  // [partial][frame col], pitch 18

  if (tid < NF) {
    int f = min(max(fbase + tid, 0), T - 1);
    Fsh[tid] = six_f0[(size_t)(b * T + f) * STR + sidx];
  } else if (tid < 2 * NF) {
    int i = tid - NF;
    int f = min(max(fbase + i, 0), T - 1);
    Lsh[i] = loud[f];
  }
  __syncthreads();

  // Stage Nyquist-masked amplitudes, transposed to [p][frame col].
  for (int i = tid; i < P * NF; i += 256) {
    int p = i / NF, fl = i - p * NF;
    int f = min(max(fbase + fl, 0), T - 1);
    float F = Fsh[fl];
    float cv = cb[((size_t)b * P + p) * T + f];
    ampsT[p][fl] = ((float)(p + 1) * F < NYQ) ? cv : 0.0f;
  }
  __syncthreads();

  const int seg = G0 + (tid >> 4);  // this thread's segment (may exceed 1000)
  const int q = tid & 15;
  const int lo_l = tid >> 4;        // = (seg-1) - fbase, uniform (clamp-free)
  const float Flo = Fsh[lo_l];
  const float Fhi = Fsh[lo_l + 1];
  const float Llo = Lsh[lo_l];
  const float dL = Lsh[lo_l + 1] - Llo;
  const float dF = Fhi - Flo;
  const float base = segbase[b * SEG_PITCH + min(seg, SEG_PITCH - 1)];
  const int kadj = (seg == 0) ? -32 : 0;  // head segment starts mid-window
  const int kp = q * 4;

  float wj[4], twoC[4], scur[4], sprev[4], accj[4];
#pragma unroll
  for (int j = 0; j < 4; ++j) {
    int k = kp + j + kadj;
    float kf1 = (float)(k + 1);
    float local = (kf1 * Flo + dF * kf1 * kf1 * (1.0f / 128.0f)) * INV_SR;
    float phi = fracf_(base + local);
    wj[j] = ((float)k + 0.5f) * (1.0f / 64.0f);
    twoC[j] = 2.0f * cos2pi(phi);
    scur[j] = sin2pi(phi);
    sprev[j] = 0.0f;
    accj[j] = 0.0f;
  }

  const float Fmn = fminf(Flo, Fhi);
  const int pmax = min(P, (int)(NYQ / Fmn) + 1);

  const float* row = &ampsT[0][lo_l];
#pragma unroll 2
  for (int p = 0; p < pmax; ++p) {
    float a0 = row[p * (NF + 1)];
    float a1 = row[p * (NF + 1) + 1];
    float d = a1 - a0;
#pragma unroll
    for (int j = 0; j < 4; ++j) {
      float amp = fmaf(wj[j], d, a0);
      accj[j] = fmaf(amp, scur[j], accj[j]);
      float sn = fmaf(twoC[j], scur[j], -sprev[j]);
      sprev[j] = scur[j];
      scur[j] = sn;
    }
  }

  // live iff all 4 samples in-range: seg 0 -> upper half only, seg 1000 ->
  // lower half only, seg > 1000 -> none.
  bool live = (seg < 1000) ? !(seg == 0 && q < 8) : (seg == 1000 && q < 8);
  if (live) {
    int s0 = seg * 64 - 32 + kp;  // multiple of 4 -> 16B-aligned float4
    float4 r;
    r.x = accj[0] * 0.02f * fmaf(wj[0], dL, Llo);
    r.y = accj[1] * 0.02f * fmaf(wj[1], dL, Llo);
    r.z = accj[2] * 0.02f * fmaf(wj[2], dL, Llo);
    r.w = accj[3] * 0.02f * fmaf(wj[3], dL, Llo);
    *(float4*)(out + (size_t)b * S + s0) = r;
  }
}

extern "C" void kernel_launch(void* const* d_in, const int* in_sizes, int n_in,
                              void* d_out, int out_size, void* d_ws,
                              size_t ws_size, hipStream_t stream) {
  const float* six_f0 = (const float*)d_in[0];
  const float* c = (const float*)d_in[1];
  const float* a = (const float*)d_in[2];
  const int* sidx = (const int*)d_in[3];
  float* out = (float*)d_out;
  float* segbase = (float*)d_ws;  // B * SEG_PITCH floats = 64 KiB

  hipLaunchKernelGGL(k_segbase, dim3(B), dim3(256), 0, stream, six_f0, sidx,
                     segbase);
  hipLaunchKernelGGL(k_synth, dim3(NBLK, B), dim3(256), 0, stream, six_f0, c,
                     a, sidx, segbase, out);
}

// Round 3
// 86.166 us; speedup vs baseline: 1.1005x; 1.0131x over previous
//
#include <hip/hip_runtime.h>
#include <math.h>

// Problem shapes (fixed by setup_inputs)
constexpr int B = 16, T = 1000, P = 64, STR = 6, SCALE = 64;
constexpr int S = T * SCALE;      // 64000 samples per batch row
constexpr int SEGS_PER_BLK = 16;  // segments per block
constexpr int NF = 17;            // frame columns staged (16 segs + 1)
constexpr int NBLK = 63;          // ceil(1001/16)
#define NYQ 11025.0f
#define INV_SR (1.0f / 22050.0f)
#define INV_SR_D (1.0 / 22050.0)

__device__ __forceinline__ float fracf_(float x) {
#if __has_builtin(__builtin_amdgcn_fractf)
  return __builtin_amdgcn_fractf(x);
#else
  return x - floorf(x);
#endif
}
__device__ __forceinline__ float sin2pi(float r) {
#if __has_builtin(__builtin_amdgcn_sinf)
  return __builtin_amdgcn_sinf(r);  // v_sin_f32: input in revolutions
#else
  return __sinf(r * 6.28318530717958647692f);
#endif
}
__device__ __forceinline__ float cos2pi(float r) {
#if __has_builtin(__builtin_amdgcn_cosf)
  return __builtin_amdgcn_cosf(r);
#else
  return __cosf(r * 6.28318530717958647692f);
#endif
}

// Single fused kernel. Block = (b, 16 consecutive segments).
// Phase base is computed per-block: base(G0) in Hz-samples is
//   G0==0: 0
//   G0==1: 32*F0                      (head segment)
//   G0>=2: 32*F0 + 32*(F0 + 2*Sum(F[1..G0-2]) + F[G0-1])
// via a block-wide fp64 reduction (six_f0 is L2-resident). Per-thread
// segment offset from the staged Fsh window. Then a thread owns 4
// consecutive samples of ONE segment; sin via Chebyshev recurrence.
__global__ __launch_bounds__(256) void k_fused(
    const float* __restrict__ six_f0, const float* __restrict__ c,
    const float* __restrict__ a, const int* __restrict__ sidx_p,
    float* __restrict__ out) {
  const int b = blockIdx.y;
  const int G0 = blockIdx.x * SEGS_PER_BLK;
  const int fbase = G0 - 1;  // frame of LDS column 0 (clamped at edges)
  const int tid = threadIdx.x;
  const int sidx = sidx_p[0] - 1;
  const float* f0row = six_f0 + (size_t)b * T * STR + sidx;  // stride STR
  const float* cb = c + (size_t)sidx * B * P * T;
  const float* loud = a + (size_t)sidx * B * T + (size_t)b * T;

  __shared__ float Fsh[NF];
  __shared__ float Lsh[NF];
  __shared__ double wtot[4];
  __shared__ float ampsT[P][NF + 1];  // [partial][frame col], pitch 18

  // Phase A: stage F and L windows; every thread also accumulates its slice
  // of Sum(F[1..G0-2]) in fp64.
  if (tid < NF) {
    int f = min(max(fbase + tid, 0), T - 1);
    Fsh[tid] = f0row[(size_t)f * STR];
  } else if (tid < 2 * NF) {
    int i = tid - NF;
    int f = min(max(fbase + i, 0), T - 1);
    Lsh[i] = loud[f];
  }
  double psum = 0.0;
  for (int t = 1 + tid; t <= G0 - 2; t += 256)
    psum += (double)f0row[(size_t)t * STR];
  __syncthreads();

  // Phase B: amplitude staging (Nyquist-masked, transposed) + wave-reduce.
  for (int i = tid; i < P * NF; i += 256) {
    int p = i / NF, fl = i - p * NF;
    int f = min(max(fbase + fl, 0), T - 1);
    float F = Fsh[fl];
    float cv = cb[((size_t)b * P + p) * T + f];
    ampsT[p][fl] = ((float)(p + 1) * F < NYQ) ? cv : 0.0f;
  }
  {
    double v = psum;
    for (int off = 32; off >= 1; off >>= 1) v += __shfl_down(v, off, 64);
    if ((tid & 63) == 0) wtot[tid >> 6] = v;
  }
  __syncthreads();

  // Phase C: per-thread phase base.
  const double Ssum = wtot[0] + wtot[1] + wtot[2] + wtot[3];
  const double F0d = (double)f0row[0];
  double baseHz;
  if (G0 == 0)
    baseHz = 0.0;
  else if (G0 == 1)
    baseHz = 32.0 * F0d;
  else
    baseHz = 32.0 * F0d + 32.0 * (F0d + 2.0 * Ssum + (double)Fsh[0]);

  const int m = tid >> 4;
  const int seg = G0 + m;  // may exceed 1000 (dead lanes)
  for (int g = G0; g < seg; ++g) {
    double ss;
    if (g == 0)
      ss = 32.0 * F0d;
    else if (g >= T)
      ss = 32.0 * (double)Fsh[g - 1 - fbase];
    else
      ss = 32.0 * ((double)Fsh[g - 1 - fbase] + (double)Fsh[g - fbase]);
    baseHz += ss;
  }
  double phd = baseHz * INV_SR_D;
  phd -= floor(phd);
  const float base = (float)phd;

  const int q = tid & 15;
  const int lo_l = m;  // = (seg-1) - fbase, uniform per 16-thread group
  const float Flo = Fsh[lo_l];
  const float Fhi = Fsh[lo_l + 1];
  const float Llo = Lsh[lo_l];
  const float dL = Lsh[lo_l + 1] - Llo;
  const float dF = Fhi - Flo;
  const int kadj = (seg == 0) ? -32 : 0;  // head segment starts mid-window
  const int kp = q * 4;

  float wj[4], twoC[4], scur[4], sprev[4], accj[4];
#pragma unroll
  for (int j = 0; j < 4; ++j) {
    int k = kp + j + kadj;
    float kf1 = (float)(k + 1);
    float local = (kf1 * Flo + dF * kf1 * kf1 * (1.0f / 128.0f)) * INV_SR;
    float phi = fracf_(base + local);
    wj[j] = ((float)k + 0.5f) * (1.0f / 64.0f);
    twoC[j] = 2.0f * cos2pi(phi);
    scur[j] = sin2pi(phi);
    sprev[j] = 0.0f;
    accj[j] = 0.0f;
  }

  const float Fmn = fminf(Flo, Fhi);
  const int pmax = min(P, (int)(NYQ / Fmn) + 1);

  const float* row = &ampsT[0][lo_l];
#pragma unroll 2
  for (int p = 0; p < pmax; ++p) {
    float a0 = row[p * (NF + 1)];
    float a1 = row[p * (NF + 1) + 1];
    float d = a1 - a0;
#pragma unroll
    for (int j = 0; j < 4; ++j) {
      float amp = fmaf(wj[j], d, a0);
      accj[j] = fmaf(amp, scur[j], accj[j]);
      float sn = fmaf(twoC[j], scur[j], -sprev[j]);
      sprev[j] = scur[j];
      scur[j] = sn;
    }
  }

  // live iff all 4 samples in-range: seg 0 -> upper half only, seg 1000 ->
  // lower half only, seg > 1000 -> none.
  bool live = (seg < 1000) ? !(seg == 0 && q < 8) : (seg == 1000 && q < 8);
  if (live) {
    int s0 = seg * 64 - 32 + kp;  // multiple of 4 -> 16B-aligned float4
    float4 r;
    r.x = accj[0] * 0.02f * fmaf(wj[0], dL, Llo);
    r.y = accj[1] * 0.02f * fmaf(wj[1], dL, Llo);
    r.z = accj[2] * 0.02f * fmaf(wj[2], dL, Llo);
    r.w = accj[3] * 0.02f * fmaf(wj[3], dL, Llo);
    *(float4*)(out + (size_t)b * S + s0) = r;
  }
}

extern "C" void kernel_launch(void* const* d_in, const int* in_sizes, int n_in,
                              void* d_out, int out_size, void* d_ws,
                              size_t ws_size, hipStream_t stream) {
  const float* six_f0 = (const float*)d_in[0];
  const float* c = (const float*)d_in[1];
  const float* a = (const float*)d_in[2];
  const int* sidx = (const int*)d_in[3];
  float* out = (float*)d_out;

  hipLaunchKernelGGL(k_fused, dim3(NBLK, B), dim3(256), 0, stream, six_f0, c,
                     a, sidx, out);
}